// Round 15
// baseline (981.513 us; speedup 1.0000x reference)
//
#include <hip/hip_runtime.h>
#include <cmath>

#define VOCAB 32000
#define EMB   256
#define HID   512
#define TLEN  513      // SEQ + 1
#define G4    2048     // 4*HID
#define NWG   32       // recurrence workgroups
#define SOS   1
#define NPRE  264      // precompute blocks (33*8)
#define NCVT  4000     // W_out conversion blocks (16.384M/4096)

typedef unsigned long long u64;
typedef unsigned int uivec4 __attribute__((ext_vector_type(4)));
typedef float f32x4 __attribute__((ext_vector_type(4)));
typedef short bf16x8 __attribute__((ext_vector_type(8)));

__device__ inline float fsig(float x)  { return __builtin_amdgcn_rcpf(1.f + __expf(-x)); }
__device__ inline float ftanh(float x) { return 1.f - 2.f * __builtin_amdgcn_rcpf(__expf(2.f * x) + 1.f); }
__device__ inline float fma4(f32x4 w, f32x4 h, float a) {
    return fmaf(w[0], h[0], fmaf(w[1], h[1], fmaf(w[2], h[2], fmaf(w[3], h[3], a))));
}

// split fp32 -> bf16 hi + bf16 lo (RNE both); x ~= hi + lo to ~2^-18 rel
__device__ inline void bf16split(float f, short& h, short& l) {
    unsigned u = __float_as_uint(f);
    unsigned r = u + (0x7fffu + ((u >> 16) & 1u));
    unsigned hb = r & 0xffff0000u;
    h = (short)(hb >> 16);
    float res = f - __uint_as_float(hb);
    unsigned u2 = __float_as_uint(res);
    unsigned r2 = u2 + (0x7fffu + ((u2 >> 16) & 1u));
    l = (short)(r2 >> 16);
}

// ---------------------------------------------------------------------------
// Fused pre-kernel. Blocks 0..263: Xg precompute (proven r2 structure).
// Blocks 264..4263: W_out -> split-bf16 planes Wh/Wl (16 elems/thread).
// Block 264 also zeroes pk. Runs before lstm (stream-serial).
// ---------------------------------------------------------------------------
__global__ __launch_bounds__(256) void pre_fused(
    const int* __restrict__ seq, const float* __restrict__ emb,
    const float* __restrict__ W_ih, const float* __restrict__ b_ih,
    const float* __restrict__ b_hh, const float* __restrict__ W_out,
    float* __restrict__ Xg, u64* pk,
    short* __restrict__ Wh, short* __restrict__ Wl, int do_split)
{
    __shared__ __align__(16) float ebuf[16][EMB];
    const int b   = blockIdx.x;
    const int tid = threadIdx.x;

    if (b >= NPRE) {                      // ---- conversion role ----
        if (!do_split) return;
        if (b == NPRE) {                  // zero pk[2][512]
#pragma unroll
            for (int i = 0; i < 4; ++i) pk[tid + 256 * i] = 0;
        }
        const size_t base = (size_t)(b - NPRE) * 4096 + (size_t)tid * 16;
        const float4* src = (const float4*)(W_out + base);
        float4 f0 = src[0], f1 = src[1], f2 = src[2], f3 = src[3];
        float fv[16] = { f0.x,f0.y,f0.z,f0.w, f1.x,f1.y,f1.z,f1.w,
                         f2.x,f2.y,f2.z,f2.w, f3.x,f3.y,f3.z,f3.w };
        union { short s[8]; bf16x8 v; } h0_, h1_, l0_, l1_;
#pragma unroll
        for (int e = 0; e < 8; ++e) bf16split(fv[e],     h0_.s[e], l0_.s[e]);
#pragma unroll
        for (int e = 0; e < 8; ++e) bf16split(fv[8 + e], h1_.s[e], l1_.s[e]);
        *(bf16x8*)&Wh[base]     = h0_.v;
        *(bf16x8*)&Wh[base + 8] = h1_.v;
        *(bf16x8*)&Wl[base]     = l0_.v;
        *(bf16x8*)&Wl[base + 8] = l1_.v;
        return;
    }

    // ---- precompute role (bt 0..32, br 0..7) ----
    const int bt = b % 33;
    const int br = b / 33;

    for (int tt = 0; tt < 16; ++tt) {
        int t = bt * 16 + tt;
        if (t < TLEN) {
            int tok = (t == 0) ? SOS : seq[t - 1];
            ebuf[tt][tid] = emb[(size_t)tok * EMB + tid];
        }
    }
    __syncthreads();

    const int row = br * 256 + tid;
    float acc[16];
#pragma unroll
    for (int tt = 0; tt < 16; ++tt) acc[tt] = 0.f;

    const float4* wp = (const float4*)(W_ih + (size_t)row * EMB);
#pragma unroll 4
    for (int k4 = 0; k4 < EMB / 4; ++k4) {
        float4 w = wp[k4];
#pragma unroll
        for (int tt = 0; tt < 16; ++tt) {
            float4 e = *(const float4*)&ebuf[tt][k4 * 4];
            acc[tt] = fmaf(w.x, e.x, fmaf(w.y, e.y, fmaf(w.z, e.z, fmaf(w.w, e.w, acc[tt]))));
        }
    }

    const float bias = b_ih[row] + b_hh[row];
    for (int tt = 0; tt < 16; ++tt) {
        int t = bt * 16 + tt;
        if (t < TLEN) Xg[(size_t)t * G4 + row] = acc[tt] + bias;
    }
}

// ---------------------------------------------------------------------------
// Kernel B: persistent LSTM recurrence (r14, best measured: 1.63 us/step).
// Transport: tag|float u64 single-copy-atomic words via MALL; publish via
// atomic EXCHANGE (at coherence point), poll via sc0 sc1 dwordx4. No B1
// barrier (wave-local poll->hbuf slice); pbuf double-buffered. Act lanes
// additionally emit split-bf16 hs planes for the conversion-free GEMM.
// ---------------------------------------------------------------------------
__global__ __launch_bounds__(256, 1) void lstm_recurrence(
    const float* __restrict__ Xg, const float* __restrict__ W_hh,
    const float* __restrict__ h0, const float* __restrict__ c0,
    float* __restrict__ hs, short* __restrict__ hs_h, short* __restrict__ hs_l,
    u64* pk, float* __restrict__ out_hT, float* __restrict__ out_cT)
{
    __shared__ __align__(16) float hbuf[HID];
    __shared__ float pbuf[2][256];

    const int wg  = blockIdx.x;     // 0..31
    const int tid = threadIdx.x;
    const int wv  = tid >> 6;       // k segment 0..3
    const int ln  = tid & 63;
    const int q   = ln >> 4;        // gate i,f,g,o
    const int j   = ln & 15;
    const int row = q * HID + wg * 16 + j;

    f32x4 wreg[32];
    const f32x4* wp = (const f32x4*)(W_hh + (size_t)row * HID + wv * 128);
#pragma unroll
    for (int i = 0; i < 32; ++i) wreg[i] = wp[i];

    float c = (tid < 16) ? c0[wg * 16 + tid] : 0.f;
    {
        float2 h2 = *(const float2*)&h0[tid * 2];
        hbuf[tid * 2]     = h2.x;
        hbuf[tid * 2 + 1] = h2.y;
    }
    __syncthreads();

    for (int t = 0; t < TLEN; ++t) {
        // activation lanes' Xg (4 gate rows each), issued before the poll
        float xg0 = 0.f, xg1 = 0.f, xg2 = 0.f, xg3 = 0.f;
        if (tid < 16) {
            const float* xp = Xg + (size_t)t * G4 + wg * 16 + tid;
            xg0 = xp[0]; xg1 = xp[512]; xg2 = xp[1024]; xg3 = xp[1536];
        }

        if (t > 0) {
            const unsigned tt = (unsigned)t;
            u64 sa = (u64)(uintptr_t)(pk + (size_t)(t & 1) * HID + 2 * tid);
            uivec4 r;
            do {
                asm volatile("global_load_dwordx4 %0, %1, off sc0 sc1\n\t"
                             "s_waitcnt vmcnt(0)" : "=v"(r) : "v"(sa));
            } while (r.y != tt || r.w != tt);
            hbuf[2 * tid]     = __uint_as_float(r.x);
            hbuf[2 * tid + 1] = __uint_as_float(r.z);
            asm volatile("s_waitcnt lgkmcnt(0)" ::: "memory");
            // no barrier: this wave wrote exactly the slice it reads below
        }

        // partial matvec (hbuf b128 reads are full-wave broadcasts: conflict-free)
        float a0 = 0.f, a1 = 0.f, a2 = 0.f, a3 = 0.f;
        float a4 = 0.f, a5 = 0.f, a6 = 0.f, a7 = 0.f;
        const f32x4* hp = (const f32x4*)&hbuf[wv * 128];
#pragma unroll
        for (int i = 0; i < 32; i += 8) {
            a0 = fma4(wreg[i],     hp[i],     a0);
            a1 = fma4(wreg[i + 1], hp[i + 1], a1);
            a2 = fma4(wreg[i + 2], hp[i + 2], a2);
            a3 = fma4(wreg[i + 3], hp[i + 3], a3);
            a4 = fma4(wreg[i + 4], hp[i + 4], a4);
            a5 = fma4(wreg[i + 5], hp[i + 5], a5);
            a6 = fma4(wreg[i + 6], hp[i + 6], a6);
            a7 = fma4(wreg[i + 7], hp[i + 7], a7);
        }
        pbuf[t & 1][tid] = ((a0 + a1) + (a2 + a3)) + ((a4 + a5) + (a6 + a7));
        __syncthreads();                                  // the step's ONLY barrier

        if (tid < 16) {
            const float* pb = pbuf[t & 1];
            float gi = pb[tid]      + pb[64 + tid]  + pb[128 + tid] + pb[192 + tid] + xg0;
            float gf = pb[16 + tid] + pb[80 + tid]  + pb[144 + tid] + pb[208 + tid] + xg1;
            float gg = pb[32 + tid] + pb[96 + tid]  + pb[160 + tid] + pb[224 + tid] + xg2;
            float go = pb[48 + tid] + pb[112 + tid] + pb[176 + tid] + pb[240 + tid] + xg3;
            float i_ = fsig(gi);
            float f_ = fsig(gf);
            float g_ = ftanh(gg);
            float o_ = fsig(go);
            c = fmaf(f_, c, i_ * g_);
            float h_ = o_ * ftanh(c);
            if (t < TLEN - 1) {
                // publish via atomic exchange: visible at the MALL on completion
                u64 word = ((u64)(unsigned)(t + 1) << 32) | (u64)__float_as_uint(h_);
                (void)__hip_atomic_exchange(
                    &pk[(size_t)((t + 1) & 1) * HID + wg * 16 + tid], word,
                    __ATOMIC_RELAXED, __HIP_MEMORY_SCOPE_AGENT);
            } else {
                out_hT[wg * 16 + tid] = h_;
                out_cT[wg * 16 + tid] = c;
            }
            hs[(size_t)t * HID + wg * 16 + tid] = h_;
            short hh, hl; bf16split(h_, hh, hl);          // off the poll path
            hs_h[(size_t)t * HID + wg * 16 + tid] = hh;
            hs_l[(size_t)t * HID + wg * 16 + tid] = hl;
        }
        // pbuf hazard handled by double-buffer: step t+1 writes pbuf[(t+1)&1].
    }
}

// ---------------------------------------------------------------------------
// Kernel C (pre-split path): conversion-free split-bf16 MFMA GEMM.
// Stages Ah/Al/Bh/Bl with raw short8 copies; MFMA core identical to r14.
// ---------------------------------------------------------------------------
#define GLDT 40

__global__ __launch_bounds__(256, 2) void out_gemm_pre(
    const short* __restrict__ hs_h, const short* __restrict__ hs_l,
    const short* __restrict__ Wh, const short* __restrict__ Wl,
    const float* __restrict__ b_out, float* __restrict__ out)
{
    __shared__ __align__(16) short Ah[128][GLDT];
    __shared__ __align__(16) short Al[128][GLDT];
    __shared__ __align__(16) short Bh[128][GLDT];
    __shared__ __align__(16) short Bl[128][GLDT];

    const int tb = blockIdx.x;     // 0..4
    const int vb = blockIdx.y;     // 0..249
    const int tid = threadIdx.x;
    const int w   = tid >> 6;
    const int l   = tid & 63;
    const int l15 = l & 15;
    const int lg  = l >> 4;
    const int m0 = tb * 128, n0 = vb * 128;

    const int sr = tid >> 1;
    const int kh = (tid & 1) * 16;

    f32x4 acc[2][8];
#pragma unroll
    for (int s = 0; s < 2; ++s)
#pragma unroll
        for (int cc = 0; cc < 8; ++cc) acc[s][cc] = (f32x4){0.f, 0.f, 0.f, 0.f};

    for (int k0 = 0; k0 < HID; k0 += 32) {
        {   // A: raw copies from pre-split hs planes
            int trow = m0 + sr;
            bf16x8 z = (bf16x8)(short)0;
            bf16x8 ah0 = z, ah1 = z, al0 = z, al1 = z;
            if (trow < TLEN) {
                const size_t o = (size_t)trow * HID + k0 + kh;
                ah0 = *(const bf16x8*)&hs_h[o];
                ah1 = *(const bf16x8*)&hs_h[o + 8];
                al0 = *(const bf16x8*)&hs_l[o];
                al1 = *(const bf16x8*)&hs_l[o + 8];
            }
            *(bf16x8*)&Ah[sr][kh]     = ah0;
            *(bf16x8*)&Ah[sr][kh + 8] = ah1;
            *(bf16x8*)&Al[sr][kh]     = al0;
            *(bf16x8*)&Al[sr][kh + 8] = al1;
        }
        {   // B: raw copies from pre-split W_out planes
            const size_t o = (size_t)(n0 + sr) * HID + k0 + kh;
            *(bf16x8*)&Bh[sr][kh]     = *(const bf16x8*)&Wh[o];
            *(bf16x8*)&Bh[sr][kh + 8] = *(const bf16x8*)&Wh[o + 8];
            *(bf16x8*)&Bl[sr][kh]     = *(const bf16x8*)&Wl[o];
            *(bf16x8*)&Bl[sr][kh + 8] = *(const bf16x8*)&Wl[o + 8];
        }
        __syncthreads();

        bf16x8 ah[2], al2[2];
#pragma unroll
        for (int s = 0; s < 2; ++s) {
            ah[s]  = *(const bf16x8*)&Ah[32 * w + 16 * s + l15][8 * lg];
            al2[s] = *(const bf16x8*)&Al[32 * w + 16 * s + l15][8 * lg];
        }
#pragma unroll
        for (int cc = 0; cc < 8; ++cc) {
            bf16x8 bh = *(const bf16x8*)&Bh[16 * cc + l15][8 * lg];
            bf16x8 bl = *(const bf16x8*)&Bl[16 * cc + l15][8 * lg];
#pragma unroll
            for (int s = 0; s < 2; ++s) {
                acc[s][cc] = __builtin_amdgcn_mfma_f32_16x16x32_bf16(ah[s],  bh, acc[s][cc], 0, 0, 0);
                acc[s][cc] = __builtin_amdgcn_mfma_f32_16x16x32_bf16(ah[s],  bl, acc[s][cc], 0, 0, 0);
                acc[s][cc] = __builtin_amdgcn_mfma_f32_16x16x32_bf16(al2[s], bh, acc[s][cc], 0, 0, 0);
            }
        }
        __syncthreads();
    }

#pragma unroll
    for (int cc = 0; cc < 8; ++cc) {
        int col = n0 + 16 * cc + l15;
        float bo = b_out[col];
#pragma unroll
        for (int s = 0; s < 2; ++s) {
            int rbase = m0 + 32 * w + 16 * s + lg * 4;
#pragma unroll
            for (int r = 0; r < 4; ++r) {
                int trow = rbase + r;
                if (trow < TLEN) out[(size_t)trow * VOCAB + col] = acc[s][cc][r] + bo;
            }
        }
    }
}

// ---------------------------------------------------------------------------
// Kernel C (fallback, r14 proven): converts fp32 -> split-bf16 in-kernel.
// ---------------------------------------------------------------------------
__global__ __launch_bounds__(256, 2) void out_gemm_mfma(
    const float* __restrict__ hs, const float* __restrict__ W_out,
    const float* __restrict__ b_out, float* __restrict__ out)
{
    __shared__ __align__(16) short Ah[128][GLDT];
    __shared__ __align__(16) short Al[128][GLDT];
    __shared__ __align__(16) short Bh[128][GLDT];
    __shared__ __align__(16) short Bl[128][GLDT];

    const int tb = blockIdx.x;
    const int vb = blockIdx.y;
    const int tid = threadIdx.x;
    const int w   = tid >> 6;
    const int l   = tid & 63;
    const int l15 = l & 15;
    const int lg  = l >> 4;
    const int m0 = tb * 128, n0 = vb * 128;

    const int sr = tid >> 1;
    const int kh = (tid & 1) * 16;

    f32x4 acc[2][8];
#pragma unroll
    for (int s = 0; s < 2; ++s)
#pragma unroll
        for (int cc = 0; cc < 8; ++cc) acc[s][cc] = (f32x4){0.f, 0.f, 0.f, 0.f};

    for (int k0 = 0; k0 < HID; k0 += 32) {
        {
            int trow = m0 + sr;
            float4 fa0 = make_float4(0.f,0.f,0.f,0.f), fa1 = fa0, fa2 = fa0, fa3 = fa0;
            if (trow < TLEN) {
                const float4* ap = (const float4*)(hs + (size_t)trow * HID + k0 + kh);
                fa0 = ap[0]; fa1 = ap[1]; fa2 = ap[2]; fa3 = ap[3];
            }
            float fv[16] = { fa0.x,fa0.y,fa0.z,fa0.w, fa1.x,fa1.y,fa1.z,fa1.w,
                             fa2.x,fa2.y,fa2.z,fa2.w, fa3.x,fa3.y,fa3.z,fa3.w };
#pragma unroll
            for (int g = 0; g < 2; ++g) {
                union { short s[8]; bf16x8 v; } ph, pl;
#pragma unroll
                for (int e = 0; e < 8; ++e) bf16split(fv[g * 8 + e], ph.s[e], pl.s[e]);
                *(bf16x8*)&Ah[sr][kh + 8 * g] = ph.v;
                *(bf16x8*)&Al[sr][kh + 8 * g] = pl.v;
            }
        }
        {
            const float4* bp = (const float4*)(W_out + (size_t)(n0 + sr) * HID + k0 + kh);
            float4 fb0 = bp[0], fb1 = bp[1], fb2 = bp[2], fb3 = bp[3];
            float fv[16] = { fb0.x,fb0.y,fb0.z,fb0.w, fb1.x,fb1.y,fb1.z,fb1.w,
                             fb2.x,fb2.y,fb2.z,fb2.w, fb3.x,fb3.y,fb3.z,fb3.w };
#pragma unroll
            for (int g = 0; g < 2; ++g) {
                union { short s[8]; bf16x8 v; } ph, pl;
#pragma unroll
                for (int e = 0; e < 8; ++e) bf16split(fv[g * 8 + e], ph.s[e], pl.s[e]);
                *(bf16x8*)&Bh[sr][kh + 8 * g] = ph.v;
                *(bf16x8*)&Bl[sr][kh + 8 * g] = pl.v;
            }
        }
        __syncthreads();

        bf16x8 ah[2], al2[2];
#pragma unroll
        for (int s = 0; s < 2; ++s) {
            ah[s]  = *(const bf16x8*)&Ah[32 * w + 16 * s + l15][8 * lg];
            al2[s] = *(const bf16x8*)&Al[32 * w + 16 * s + l15][8 * lg];
        }
#pragma unroll
        for (int cc = 0; cc < 8; ++cc) {
            bf16x8 bh = *(const bf16x8*)&Bh[16 * cc + l15][8 * lg];
            bf16x8 bl = *(const bf16x8*)&Bl[16 * cc + l15][8 * lg];
#pragma unroll
            for (int s = 0; s < 2; ++s) {
                acc[s][cc] = __builtin_amdgcn_mfma_f32_16x16x32_bf16(ah[s],  bh, acc[s][cc], 0, 0, 0);
                acc[s][cc] = __builtin_amdgcn_mfma_f32_16x16x32_bf16(ah[s],  bl, acc[s][cc], 0, 0, 0);
                acc[s][cc] = __builtin_amdgcn_mfma_f32_16x16x32_bf16(al2[s], bh, acc[s][cc], 0, 0, 0);
            }
        }
        __syncthreads();
    }

#pragma unroll
    for (int cc = 0; cc < 8; ++cc) {
        int col = n0 + 16 * cc + l15;
        float bo = b_out[col];
#pragma unroll
        for (int s = 0; s < 2; ++s) {
            int rbase = m0 + 32 * w + 16 * s + lg * 4;
#pragma unroll
            for (int r = 0; r < 4; ++r) {
                int trow = rbase + r;
                if (trow < TLEN) out[(size_t)trow * VOCAB + col] = acc[s][cc][r] + bo;
            }
        }
    }
}

// ---------------------------------------------------------------------------
extern "C" void kernel_launch(void* const* d_in, const int* in_sizes, int n_in,
                              void* d_out, int out_size, void* d_ws, size_t ws_size,
                              hipStream_t stream)
{
    const int*   seq   = (const int*)  d_in[0];
    const float* h0    = (const float*)d_in[1];
    const float* c0    = (const float*)d_in[2];
    const float* emb   = (const float*)d_in[3];
    const float* W_ih  = (const float*)d_in[4];
    const float* W_hh  = (const float*)d_in[5];
    const float* b_ih  = (const float*)d_in[6];
    const float* b_hh  = (const float*)d_in[7];
    const float* W_out = (const float*)d_in[8];
    const float* b_out = (const float*)d_in[9];

    float* out_logits = (float*)d_out;                      // [513][32000]
    float* out_hT     = out_logits + (size_t)TLEN * VOCAB;  // [512]
    float* out_cT     = out_hT + HID;                       // [512]

    // workspace layout
    char*  base = (char*)d_ws;
    float* Xg   = (float*)base;                               //  4,202,496 B
    float* hs   = (float*)(base + 4202496);                   //  1,050,624 B
    u64*   pk   = (u64*)  (base + 4202496 + 1050624);         //      8,192 B
    short* hs_h = (short*)(base + 5261312);                   //    525,312 B
    short* hs_l = (short*)(base + 5261312 + 525312);          //    525,312 B
    short* Wh   = (short*)(base + 6311936);                   // 32,768,000 B
    short* Wl   = (short*)(base + 6311936 + 32768000);        // 32,768,000 B
    const size_t need_pre = 6311936ull + 2ull * 32768000ull;  // 71,847,936 B

    const int use_pre = (ws_size >= need_pre) ? 1 : 0;

    if (use_pre) {
        pre_fused<<<NPRE + NCVT, 256, 0, stream>>>(seq, emb, W_ih, b_ih, b_hh, W_out,
                                                   Xg, pk, Wh, Wl, 1);
        lstm_recurrence<<<NWG, 256, 0, stream>>>(Xg, W_hh, h0, c0, hs, hs_h, hs_l, pk,
                                                 out_hT, out_cT);
        out_gemm_pre<<<dim3(5, 250), 256, 0, stream>>>(hs_h, hs_l, Wh, Wl, b_out, out_logits);
    } else {
        (void)hipMemsetAsync(pk, 0, 2 * HID * sizeof(u64), stream);
        pre_fused<<<NPRE, 256, 0, stream>>>(seq, emb, W_ih, b_ih, b_hh, W_out,
                                            Xg, pk, hs_h /*unused*/, hs_l /*unused*/, 0);
        lstm_recurrence<<<NWG, 256, 0, stream>>>(Xg, W_hh, h0, c0, hs, hs_h, hs_l, pk,
                                                 out_hT, out_cT);
        out_gemm_mfma<<<dim3(5, 250), 256, 0, stream>>>(hs, W_out, b_out, out_logits);
    }
}

// Round 16
// 967.976 us; speedup vs baseline: 1.0140x; 1.0140x over previous
//
#include <hip/hip_runtime.h>
#include <cmath>

#define VOCAB 32000
#define EMB   256
#define HID   512
#define TLEN  513      // SEQ + 1
#define G4    2048     // 4*HID
#define NWG   32       // recurrence workgroups
#define NCONV 224      // conversion workgroups (blocks 32..255 of lstm launch)
#define SOS   1
#define NPRE  264      // precompute blocks (33*8)
#define WOUT_ELEMS 16384000ull   // 32000*512

typedef unsigned long long u64;
typedef unsigned int uivec4 __attribute__((ext_vector_type(4)));
typedef float f32x4 __attribute__((ext_vector_type(4)));
typedef short bf16x8 __attribute__((ext_vector_type(8)));

__device__ inline float fsig(float x)  { return __builtin_amdgcn_rcpf(1.f + __expf(-x)); }
__device__ inline float ftanh(float x) { return 1.f - 2.f * __builtin_amdgcn_rcpf(__expf(2.f * x) + 1.f); }
__device__ inline float fma4(f32x4 w, f32x4 h, float a) {
    return fmaf(w[0], h[0], fmaf(w[1], h[1], fmaf(w[2], h[2], fmaf(w[3], h[3], a))));
}

// split fp32 -> bf16 hi + bf16 lo (RNE both); x ~= hi + lo to ~2^-18 rel
__device__ inline void bf16split(float f, short& h, short& l) {
    unsigned u = __float_as_uint(f);
    unsigned r = u + (0x7fffu + ((u >> 16) & 1u));
    unsigned hb = r & 0xffff0000u;
    h = (short)(hb >> 16);
    float res = f - __uint_as_float(hb);
    unsigned u2 = __float_as_uint(res);
    unsigned r2 = u2 + (0x7fffu + ((u2 >> 16) & 1u));
    l = (short)(r2 >> 16);
}

// ---------------------------------------------------------------------------
// Kernel A: Xg precompute (proven r2 structure). Block (0,0) zeroes pk.
// ---------------------------------------------------------------------------
__global__ __launch_bounds__(256) void precompute_gates(
    const int* __restrict__ seq, const float* __restrict__ emb,
    const float* __restrict__ W_ih, const float* __restrict__ b_ih,
    const float* __restrict__ b_hh, float* __restrict__ Xg, u64* pk)
{
    __shared__ __align__(16) float ebuf[16][EMB];
    const int bt = blockIdx.x;   // 0..32
    const int br = blockIdx.y;   // 0..7
    const int tid = threadIdx.x;

    if (bt == 0 && br == 0) {    // zero pk[2][512]
#pragma unroll
        for (int i = 0; i < 4; ++i) pk[tid + 256 * i] = 0;
    }

    for (int tt = 0; tt < 16; ++tt) {
        int t = bt * 16 + tt;
        if (t < TLEN) {
            int tok = (t == 0) ? SOS : seq[t - 1];
            ebuf[tt][tid] = emb[(size_t)tok * EMB + tid];
        }
    }
    __syncthreads();

    const int row = br * 256 + tid;
    float acc[16];
#pragma unroll
    for (int tt = 0; tt < 16; ++tt) acc[tt] = 0.f;

    const float4* wp = (const float4*)(W_ih + (size_t)row * EMB);
#pragma unroll 4
    for (int k4 = 0; k4 < EMB / 4; ++k4) {
        float4 w = wp[k4];
#pragma unroll
        for (int tt = 0; tt < 16; ++tt) {
            float4 e = *(const float4*)&ebuf[tt][k4 * 4];
            acc[tt] = fmaf(w.x, e.x, fmaf(w.y, e.y, fmaf(w.z, e.z, fmaf(w.w, e.w, acc[tt]))));
        }
    }

    const float bias = b_ih[row] + b_hh[row];
    for (int tt = 0; tt < 16; ++tt) {
        int t = bt * 16 + tt;
        if (t < TLEN) Xg[(size_t)t * G4 + row] = acc[tt] + bias;
    }
}

// ---------------------------------------------------------------------------
// Kernel B: blocks 0..31 = persistent LSTM recurrence (r14 best: 1.63us/step);
// blocks 32..255 = W_out split-bf16 conversion (pure streaming, no polls,
// disjoint CUs at 1 block/CU -> overlaps the recurrence for free; finishes
// in its first ~5% and stream-order guarantees completion before the GEMM).
// Transport: tag|float u64 single-copy-atomic words via MALL; publish via
// atomic EXCHANGE, poll via sc0 sc1 dwordx4. No B1 barrier; pbuf dbuffered.
// Act lanes emit split-bf16 hs planes for the conversion-free GEMM.
// ---------------------------------------------------------------------------
__global__ __launch_bounds__(256, 1) void lstm_recurrence(
    const float* __restrict__ Xg, const float* __restrict__ W_hh,
    const float* __restrict__ h0, const float* __restrict__ c0,
    const float* __restrict__ W_out, short* __restrict__ Wh, short* __restrict__ Wl,
    float* __restrict__ hs, short* __restrict__ hs_h, short* __restrict__ hs_l,
    u64* pk, float* __restrict__ out_hT, float* __restrict__ out_cT, int do_conv)
{
    __shared__ __align__(16) float hbuf[HID];
    __shared__ float pbuf[2][256];

    const int tid = threadIdx.x;

    if (blockIdx.x >= NWG) {
        // ---------------- conversion role (streams W_out once) ----------------
        if (!do_conv) return;
        const int cb = blockIdx.x - NWG;                 // 0..223
        const size_t stride = (size_t)NCONV * 256 * 16;  // floats per sweep
        for (size_t i = ((size_t)cb * 256 + tid) * 16; i < WOUT_ELEMS; i += stride) {
            const float4* src = (const float4*)(W_out + i);
            float4 f0 = src[0], f1 = src[1], f2 = src[2], f3 = src[3];
            float fv[16] = { f0.x,f0.y,f0.z,f0.w, f1.x,f1.y,f1.z,f1.w,
                             f2.x,f2.y,f2.z,f2.w, f3.x,f3.y,f3.z,f3.w };
            union { short s[8]; bf16x8 v; } h0_, h1_, l0_, l1_;
#pragma unroll
            for (int e = 0; e < 8; ++e) bf16split(fv[e],     h0_.s[e], l0_.s[e]);
#pragma unroll
            for (int e = 0; e < 8; ++e) bf16split(fv[8 + e], h1_.s[e], l1_.s[e]);
            *(bf16x8*)&Wh[i]     = h0_.v;
            *(bf16x8*)&Wh[i + 8] = h1_.v;
            *(bf16x8*)&Wl[i]     = l0_.v;
            *(bf16x8*)&Wl[i + 8] = l1_.v;
        }
        return;
    }

    // ---------------- recurrence role (r14 core, unchanged) ----------------
    const int wg  = blockIdx.x;     // 0..31
    const int wv  = tid >> 6;       // k segment 0..3
    const int ln  = tid & 63;
    const int q   = ln >> 4;        // gate i,f,g,o
    const int j   = ln & 15;
    const int row = q * HID + wg * 16 + j;

    f32x4 wreg[32];
    const f32x4* wp = (const f32x4*)(W_hh + (size_t)row * HID + wv * 128);
#pragma unroll
    for (int i = 0; i < 32; ++i) wreg[i] = wp[i];

    float c = (tid < 16) ? c0[wg * 16 + tid] : 0.f;
    {
        float2 h2 = *(const float2*)&h0[tid * 2];
        hbuf[tid * 2]     = h2.x;
        hbuf[tid * 2 + 1] = h2.y;
    }
    __syncthreads();

    for (int t = 0; t < TLEN; ++t) {
        // activation lanes' Xg (4 gate rows each), issued before the poll
        float xg0 = 0.f, xg1 = 0.f, xg2 = 0.f, xg3 = 0.f;
        if (tid < 16) {
            const float* xp = Xg + (size_t)t * G4 + wg * 16 + tid;
            xg0 = xp[0]; xg1 = xp[512]; xg2 = xp[1024]; xg3 = xp[1536];
        }

        if (t > 0) {
            const unsigned tt = (unsigned)t;
            u64 sa = (u64)(uintptr_t)(pk + (size_t)(t & 1) * HID + 2 * tid);
            uivec4 r;
            do {
                asm volatile("global_load_dwordx4 %0, %1, off sc0 sc1\n\t"
                             "s_waitcnt vmcnt(0)" : "=v"(r) : "v"(sa));
            } while (r.y != tt || r.w != tt);
            hbuf[2 * tid]     = __uint_as_float(r.x);
            hbuf[2 * tid + 1] = __uint_as_float(r.z);
            asm volatile("s_waitcnt lgkmcnt(0)" ::: "memory");
            // no barrier: this wave wrote exactly the slice it reads below
        }

        // partial matvec (hbuf b128 reads are full-wave broadcasts: conflict-free)
        float a0 = 0.f, a1 = 0.f, a2 = 0.f, a3 = 0.f;
        float a4 = 0.f, a5 = 0.f, a6 = 0.f, a7 = 0.f;
        const f32x4* hp = (const f32x4*)&hbuf[wv * 128];
#pragma unroll
        for (int i = 0; i < 32; i += 8) {
            a0 = fma4(wreg[i],     hp[i],     a0);
            a1 = fma4(wreg[i + 1], hp[i + 1], a1);
            a2 = fma4(wreg[i + 2], hp[i + 2], a2);
            a3 = fma4(wreg[i + 3], hp[i + 3], a3);
            a4 = fma4(wreg[i + 4], hp[i + 4], a4);
            a5 = fma4(wreg[i + 5], hp[i + 5], a5);
            a6 = fma4(wreg[i + 6], hp[i + 6], a6);
            a7 = fma4(wreg[i + 7], hp[i + 7], a7);
        }
        pbuf[t & 1][tid] = ((a0 + a1) + (a2 + a3)) + ((a4 + a5) + (a6 + a7));
        __syncthreads();                                  // the step's ONLY barrier

        if (tid < 16) {
            const float* pb = pbuf[t & 1];
            float gi = pb[tid]      + pb[64 + tid]  + pb[128 + tid] + pb[192 + tid] + xg0;
            float gf = pb[16 + tid] + pb[80 + tid]  + pb[144 + tid] + pb[208 + tid] + xg1;
            float gg = pb[32 + tid] + pb[96 + tid]  + pb[160 + tid] + pb[224 + tid] + xg2;
            float go = pb[48 + tid] + pb[112 + tid] + pb[176 + tid] + pb[240 + tid] + xg3;
            float i_ = fsig(gi);
            float f_ = fsig(gf);
            float g_ = ftanh(gg);
            float o_ = fsig(go);
            c = fmaf(f_, c, i_ * g_);
            float h_ = o_ * ftanh(c);
            if (t < TLEN - 1) {
                // publish via atomic exchange: visible at the MALL on completion
                u64 word = ((u64)(unsigned)(t + 1) << 32) | (u64)__float_as_uint(h_);
                (void)__hip_atomic_exchange(
                    &pk[(size_t)((t + 1) & 1) * HID + wg * 16 + tid], word,
                    __ATOMIC_RELAXED, __HIP_MEMORY_SCOPE_AGENT);
            } else {
                out_hT[wg * 16 + tid] = h_;
                out_cT[wg * 16 + tid] = c;
            }
            hs[(size_t)t * HID + wg * 16 + tid] = h_;
            short hh, hl; bf16split(h_, hh, hl);          // off the poll path
            hs_h[(size_t)t * HID + wg * 16 + tid] = hh;
            hs_l[(size_t)t * HID + wg * 16 + tid] = hl;
        }
        // pbuf hazard handled by double-buffer: step t+1 writes pbuf[(t+1)&1].
    }
}

// ---------------------------------------------------------------------------
// Kernel C (pre-split path): conversion-free split-bf16 MFMA GEMM (r15 proven).
// ---------------------------------------------------------------------------
#define GLDT 40

__global__ __launch_bounds__(256, 2) void out_gemm_pre(
    const short* __restrict__ hs_h, const short* __restrict__ hs_l,
    const short* __restrict__ Wh, const short* __restrict__ Wl,
    const float* __restrict__ b_out, float* __restrict__ out)
{
    __shared__ __align__(16) short Ah[128][GLDT];
    __shared__ __align__(16) short Al[128][GLDT];
    __shared__ __align__(16) short Bh[128][GLDT];
    __shared__ __align__(16) short Bl[128][GLDT];

    const int tb = blockIdx.x;     // 0..4
    const int vb = blockIdx.y;     // 0..249
    const int tid = threadIdx.x;
    const int w   = tid >> 6;
    const int l   = tid & 63;
    const int l15 = l & 15;
    const int lg  = l >> 4;
    const int m0 = tb * 128, n0 = vb * 128;

    const int sr = tid >> 1;
    const int kh = (tid & 1) * 16;

    f32x4 acc[2][8];
#pragma unroll
    for (int s = 0; s < 2; ++s)
#pragma unroll
        for (int cc = 0; cc < 8; ++cc) acc[s][cc] = (f32x4){0.f, 0.f, 0.f, 0.f};

    for (int k0 = 0; k0 < HID; k0 += 32) {
        {   // A: raw copies from pre-split hs planes
            int trow = m0 + sr;
            bf16x8 z = (bf16x8)(short)0;
            bf16x8 ah0 = z, ah1 = z, al0 = z, al1 = z;
            if (trow < TLEN) {
                const size_t o = (size_t)trow * HID + k0 + kh;
                ah0 = *(const bf16x8*)&hs_h[o];
                ah1 = *(const bf16x8*)&hs_h[o + 8];
                al0 = *(const bf16x8*)&hs_l[o];
                al1 = *(const bf16x8*)&hs_l[o + 8];
            }
            *(bf16x8*)&Ah[sr][kh]     = ah0;
            *(bf16x8*)&Ah[sr][kh + 8] = ah1;
            *(bf16x8*)&Al[sr][kh]     = al0;
            *(bf16x8*)&Al[sr][kh + 8] = al1;
        }
        {   // B: raw copies from pre-split W_out planes
            const size_t o = (size_t)(n0 + sr) * HID + k0 + kh;
            *(bf16x8*)&Bh[sr][kh]     = *(const bf16x8*)&Wh[o];
            *(bf16x8*)&Bh[sr][kh + 8] = *(const bf16x8*)&Wh[o + 8];
            *(bf16x8*)&Bl[sr][kh]     = *(const bf16x8*)&Wl[o];
            *(bf16x8*)&Bl[sr][kh + 8] = *(const bf16x8*)&Wl[o + 8];
        }
        __syncthreads();

        bf16x8 ah[2], al2[2];
#pragma unroll
        for (int s = 0; s < 2; ++s) {
            ah[s]  = *(const bf16x8*)&Ah[32 * w + 16 * s + l15][8 * lg];
            al2[s] = *(const bf16x8*)&Al[32 * w + 16 * s + l15][8 * lg];
        }
#pragma unroll
        for (int cc = 0; cc < 8; ++cc) {
            bf16x8 bh = *(const bf16x8*)&Bh[16 * cc + l15][8 * lg];
            bf16x8 bl = *(const bf16x8*)&Bl[16 * cc + l15][8 * lg];
#pragma unroll
            for (int s = 0; s < 2; ++s) {
                acc[s][cc] = __builtin_amdgcn_mfma_f32_16x16x32_bf16(ah[s],  bh, acc[s][cc], 0, 0, 0);
                acc[s][cc] = __builtin_amdgcn_mfma_f32_16x16x32_bf16(ah[s],  bl, acc[s][cc], 0, 0, 0);
                acc[s][cc] = __builtin_amdgcn_mfma_f32_16x16x32_bf16(al2[s], bh, acc[s][cc], 0, 0, 0);
            }
        }
        __syncthreads();
    }

#pragma unroll
    for (int cc = 0; cc < 8; ++cc) {
        int col = n0 + 16 * cc + l15;
        float bo = b_out[col];
#pragma unroll
        for (int s = 0; s < 2; ++s) {
            int rbase = m0 + 32 * w + 16 * s + lg * 4;
#pragma unroll
            for (int r = 0; r < 4; ++r) {
                int trow = rbase + r;
                if (trow < TLEN) out[(size_t)trow * VOCAB + col] = acc[s][cc][r] + bo;
            }
        }
    }
}

// ---------------------------------------------------------------------------
// Kernel C (fallback, r14 proven): converts fp32 -> split-bf16 in-kernel.
// ---------------------------------------------------------------------------
__global__ __launch_bounds__(256, 2) void out_gemm_mfma(
    const float* __restrict__ hs, const float* __restrict__ W_out,
    const float* __restrict__ b_out, float* __restrict__ out)
{
    __shared__ __align__(16) short Ah[128][GLDT];
    __shared__ __align__(16) short Al[128][GLDT];
    __shared__ __align__(16) short Bh[128][GLDT];
    __shared__ __align__(16) short Bl[128][GLDT];

    const int tb = blockIdx.x;
    const int vb = blockIdx.y;
    const int tid = threadIdx.x;
    const int w   = tid >> 6;
    const int l   = tid & 63;
    const int l15 = l & 15;
    const int lg  = l >> 4;
    const int m0 = tb * 128, n0 = vb * 128;

    const int sr = tid >> 1;
    const int kh = (tid & 1) * 16;

    f32x4 acc[2][8];
#pragma unroll
    for (int s = 0; s < 2; ++s)
#pragma unroll
        for (int cc = 0; cc < 8; ++cc) acc[s][cc] = (f32x4){0.f, 0.f, 0.f, 0.f};

    for (int k0 = 0; k0 < HID; k0 += 32) {
        {
            int trow = m0 + sr;
            float4 fa0 = make_float4(0.f,0.f,0.f,0.f), fa1 = fa0, fa2 = fa0, fa3 = fa0;
            if (trow < TLEN) {
                const float4* ap = (const float4*)(hs + (size_t)trow * HID + k0 + kh);
                fa0 = ap[0]; fa1 = ap[1]; fa2 = ap[2]; fa3 = ap[3];
            }
            float fv[16] = { fa0.x,fa0.y,fa0.z,fa0.w, fa1.x,fa1.y,fa1.z,fa1.w,
                             fa2.x,fa2.y,fa2.z,fa2.w, fa3.x,fa3.y,fa3.z,fa3.w };
#pragma unroll
            for (int g = 0; g < 2; ++g) {
                union { short s[8]; bf16x8 v; } ph, pl;
#pragma unroll
                for (int e = 0; e < 8; ++e) bf16split(fv[g * 8 + e], ph.s[e], pl.s[e]);
                *(bf16x8*)&Ah[sr][kh + 8 * g] = ph.v;
                *(bf16x8*)&Al[sr][kh + 8 * g] = pl.v;
            }
        }
        {
            const float4* bp = (const float4*)(W_out + (size_t)(n0 + sr) * HID + k0 + kh);
            float4 fb0 = bp[0], fb1 = bp[1], fb2 = bp[2], fb3 = bp[3];
            float fv[16] = { fb0.x,fb0.y,fb0.z,fb0.w, fb1.x,fb1.y,fb1.z,fb1.w,
                             fb2.x,fb2.y,fb2.z,fb2.w, fb3.x,fb3.y,fb3.z,fb3.w };
#pragma unroll
            for (int g = 0; g < 2; ++g) {
                union { short s[8]; bf16x8 v; } ph, pl;
#pragma unroll
                for (int e = 0; e < 8; ++e) bf16split(fv[g * 8 + e], ph.s[e], pl.s[e]);
                *(bf16x8*)&Bh[sr][kh + 8 * g] = ph.v;
                *(bf16x8*)&Bl[sr][kh + 8 * g] = pl.v;
            }
        }
        __syncthreads();

        bf16x8 ah[2], al2[2];
#pragma unroll
        for (int s = 0; s < 2; ++s) {
            ah[s]  = *(const bf16x8*)&Ah[32 * w + 16 * s + l15][8 * lg];
            al2[s] = *(const bf16x8*)&Al[32 * w + 16 * s + l15][8 * lg];
        }
#pragma unroll
        for (int cc = 0; cc < 8; ++cc) {
            bf16x8 bh = *(const bf16x8*)&Bh[16 * cc + l15][8 * lg];
            bf16x8 bl = *(const bf16x8*)&Bl[16 * cc + l15][8 * lg];
#pragma unroll
            for (int s = 0; s < 2; ++s) {
                acc[s][cc] = __builtin_amdgcn_mfma_f32_16x16x32_bf16(ah[s],  bh, acc[s][cc], 0, 0, 0);
                acc[s][cc] = __builtin_amdgcn_mfma_f32_16x16x32_bf16(ah[s],  bl, acc[s][cc], 0, 0, 0);
                acc[s][cc] = __builtin_amdgcn_mfma_f32_16x16x32_bf16(al2[s], bh, acc[s][cc], 0, 0, 0);
            }
        }
        __syncthreads();
    }

#pragma unroll
    for (int cc = 0; cc < 8; ++cc) {
        int col = n0 + 16 * cc + l15;
        float bo = b_out[col];
#pragma unroll
        for (int s = 0; s < 2; ++s) {
            int rbase = m0 + 32 * w + 16 * s + lg * 4;
#pragma unroll
            for (int r = 0; r < 4; ++r) {
                int trow = rbase + r;
                if (trow < TLEN) out[(size_t)trow * VOCAB + col] = acc[s][cc][r] + bo;
            }
        }
    }
}

// ---------------------------------------------------------------------------
extern "C" void kernel_launch(void* const* d_in, const int* in_sizes, int n_in,
                              void* d_out, int out_size, void* d_ws, size_t ws_size,
                              hipStream_t stream)
{
    const int*   seq   = (const int*)  d_in[0];
    const float* h0    = (const float*)d_in[1];
    const float* c0    = (const float*)d_in[2];
    const float* emb   = (const float*)d_in[3];
    const float* W_ih  = (const float*)d_in[4];
    const float* W_hh  = (const float*)d_in[5];
    const float* b_ih  = (const float*)d_in[6];
    const float* b_hh  = (const float*)d_in[7];
    const float* W_out = (const float*)d_in[8];
    const float* b_out = (const float*)d_in[9];

    float* out_logits = (float*)d_out;                      // [513][32000]
    float* out_hT     = out_logits + (size_t)TLEN * VOCAB;  // [512]
    float* out_cT     = out_hT + HID;                       // [512]

    // workspace layout
    char*  base = (char*)d_ws;
    float* Xg   = (float*)base;                               //  4,202,496 B
    float* hs   = (float*)(base + 4202496);                   //  1,050,624 B
    u64*   pk   = (u64*)  (base + 4202496 + 1050624);         //      8,192 B
    short* hs_h = (short*)(base + 5261312);                   //    525,312 B
    short* hs_l = (short*)(base + 5261312 + 525312);          //    525,312 B
    short* Wh   = (short*)(base + 6311936);                   // 32,768,000 B
    short* Wl   = (short*)(base + 6311936 + 32768000);        // 32,768,000 B
    const size_t need_pre = 6311936ull + 2ull * 32768000ull;  // 71,847,936 B

    const int use_pre = (ws_size >= need_pre) ? 1 : 0;

    precompute_gates<<<dim3(33, 8), 256, 0, stream>>>(seq, emb, W_ih, b_ih, b_hh, Xg, pk);
    if (use_pre) {
        // blocks 0..31 recurrence, 32..255 W_out conversion (overlapped)
        lstm_recurrence<<<NWG + NCONV, 256, 0, stream>>>(
            Xg, W_hh, h0, c0, W_out, Wh, Wl, hs, hs_h, hs_l, pk, out_hT, out_cT, 1);
        out_gemm_pre<<<dim3(5, 250), 256, 0, stream>>>(hs_h, hs_l, Wh, Wl, b_out, out_logits);
    } else {
        lstm_recurrence<<<NWG, 256, 0, stream>>>(
            Xg, W_hh, h0, c0, W_out, Wh, Wl, hs, hs_h, hs_l, pk, out_hT, out_cT, 0);
        out_gemm_mfma<<<dim3(5, 250), 256, 0, stream>>>(hs, W_out, b_out, out_logits);
    }
}

// Round 17
// 957.507 us; speedup vs baseline: 1.0251x; 1.0109x over previous
//
#include <hip/hip_runtime.h>
#include <cmath>

#define VOCAB 32000
#define EMB   256
#define HID   512
#define TLEN  513      // SEQ + 1
#define G4    2048     // 4*HID
#define NWG   32       // recurrence blocks
#define NWORK 224      // gemm worker blocks
#define GRID_MEGA 256  // 1 block/CU (LDS-forced) -> rec CUs exclusive
#define NTILE_V 250
#define NTILES  (5 * NTILE_V)   // tb 0..4
#define SOS   1

typedef unsigned long long u64;
typedef unsigned int uivec4 __attribute__((ext_vector_type(4)));
typedef unsigned int uivec2 __attribute__((ext_vector_type(2)));
typedef float f32x4 __attribute__((ext_vector_type(4)));
typedef short bf16x8 __attribute__((ext_vector_type(8)));

__device__ inline float fsig(float x)  { return __builtin_amdgcn_rcpf(1.f + __expf(-x)); }
__device__ inline float ftanh(float x) { return 1.f - 2.f * __builtin_amdgcn_rcpf(__expf(2.f * x) + 1.f); }
__device__ inline float fma4(f32x4 w, f32x4 h, float a) {
    return fmaf(w[0], h[0], fmaf(w[1], h[1], fmaf(w[2], h[2], fmaf(w[3], h[3], a))));
}

// split fp32 -> bf16 hi + bf16 lo (RNE both); x ~= hi + lo to ~2^-18 rel
__device__ inline void bf16split(float f, short& h, short& l) {
    unsigned u = __float_as_uint(f);
    unsigned r = u + (0x7fffu + ((u >> 16) & 1u));
    unsigned hb = r & 0xffff0000u;
    h = (short)(hb >> 16);
    float res = f - __uint_as_float(hb);
    unsigned u2 = __float_as_uint(res);
    unsigned r2 = u2 + (0x7fffu + ((u2 >> 16) & 1u));
    l = (short)(r2 >> 16);
}

// ---------------------------------------------------------------------------
// Kernel A: Xg precompute (proven). Block (0,0) zeroes pk + flags + queue.
// ---------------------------------------------------------------------------
__global__ __launch_bounds__(256) void precompute_gates(
    const int* __restrict__ seq, const float* __restrict__ emb,
    const float* __restrict__ W_ih, const float* __restrict__ b_ih,
    const float* __restrict__ b_hh, float* __restrict__ Xg,
    u64* pk, int* flags)
{
    __shared__ __align__(16) float ebuf[16][EMB];
    const int bt = blockIdx.x;   // 0..32
    const int br = blockIdx.y;   // 0..7
    const int tid = threadIdx.x;

    if (bt == 0 && br == 0) {
#pragma unroll
        for (int i = 0; i < 4; ++i) pk[tid + 256 * i] = 0;   // pk[2][512]
        if (tid < 16) flags[tid] = 0;                        // ready[8] + wq + spare
    }

    for (int tt = 0; tt < 16; ++tt) {
        int t = bt * 16 + tt;
        if (t < TLEN) {
            int tok = (t == 0) ? SOS : seq[t - 1];
            ebuf[tt][tid] = emb[(size_t)tok * EMB + tid];
        }
    }
    __syncthreads();

    const int row = br * 256 + tid;
    float acc[16];
#pragma unroll
    for (int tt = 0; tt < 16; ++tt) acc[tt] = 0.f;

    const float4* wp = (const float4*)(W_ih + (size_t)row * EMB);
#pragma unroll 4
    for (int k4 = 0; k4 < EMB / 4; ++k4) {
        float4 w = wp[k4];
#pragma unroll
        for (int tt = 0; tt < 16; ++tt) {
            float4 e = *(const float4*)&ebuf[tt][k4 * 4];
            acc[tt] = fmaf(w.x, e.x, fmaf(w.y, e.y, fmaf(w.z, e.z, fmaf(w.w, e.w, acc[tt]))));
        }
    }

    const float bias = b_ih[row] + b_hh[row];
    for (int tt = 0; tt < 16; ++tt) {
        int t = bt * 16 + tt;
        if (t < TLEN) Xg[(size_t)t * G4 + row] = acc[tt] + bias;
    }
}

// ---------------------------------------------------------------------------
// Mega kernel: 256 blocks, EXACTLY 1/CU (85KB LDS forces it -> rec blocks own
// their CUs; r7's CU-sharing disaster is structurally impossible).
// Blocks 0..31: r14 recurrence (pk exchange publish / sc0sc1 poll, 1.63us/step)
//   + tagged A-word publish hs_t[t*512+j] = (t+1)<<32 | bf16hi<<16 | bf16lo
//   + relaxed ready[tb] increments at t=127/255/383/511 and ready[4] at 512.
// Blocks 32..255: persistent GEMM workers. Per tile: advisory flag wait
//   (s_sleep), then tag-verified A reads (truth), B staged from W_out fp32
//   with in-kernel split (L3-resident), 3-term split-bf16 MFMA (r8-proven).
//   tb==4 (row 512 only): slim fp32 dot path.
// Hang-proof: rec never waits on workers; worker spins wait on
// independently-progressing rec blocks; queue finite.
// ---------------------------------------------------------------------------
#define GLDT 40

__global__ __launch_bounds__(256, 1) void mega(
    const float* __restrict__ Xg, const float* __restrict__ W_hh,
    const float* __restrict__ h0, const float* __restrict__ c0,
    const float* __restrict__ W_out, const float* __restrict__ b_out,
    u64* pk, u64* hs_t, int* flags,
    float* __restrict__ out, float* __restrict__ out_hT, float* __restrict__ out_cT)
{
    __shared__ __align__(16) short Ah[128][GLDT];
    __shared__ __align__(16) short Al[128][GLDT];
    __shared__ __align__(16) short Bh[128][GLDT];
    __shared__ __align__(16) short Bl[128][GLDT];
    __shared__ __align__(16) float hbuf[HID];
    __shared__ float pbuf[2][256];
    __shared__ int s_idx;
    __shared__ char lds_pad[40960];   // push LDS >80KB -> 1 block/CU guaranteed

    const int tid = threadIdx.x;
    int* ready = flags;
    int* wq    = flags + 8;

    if (blockIdx.x < NWG) {
        // ==================== recurrence role (r14 core) ====================
        lds_pad[0] = 0;   // keep pad live
        const int wg  = blockIdx.x;
        const int wv  = tid >> 6;
        const int ln  = tid & 63;
        const int q   = ln >> 4;
        const int j   = ln & 15;
        const int row = q * HID + wg * 16 + j;

        f32x4 wreg[32];
        const f32x4* wp = (const f32x4*)(W_hh + (size_t)row * HID + wv * 128);
#pragma unroll
        for (int i = 0; i < 32; ++i) wreg[i] = wp[i];

        float c = (tid < 16) ? c0[wg * 16 + tid] : 0.f;
        {
            float2 h2 = *(const float2*)&h0[tid * 2];
            hbuf[tid * 2]     = h2.x;
            hbuf[tid * 2 + 1] = h2.y;
        }
        __syncthreads();

        for (int t = 0; t < TLEN; ++t) {
            float xg0 = 0.f, xg1 = 0.f, xg2 = 0.f, xg3 = 0.f;
            if (tid < 16) {
                const float* xp = Xg + (size_t)t * G4 + wg * 16 + tid;
                xg0 = xp[0]; xg1 = xp[512]; xg2 = xp[1024]; xg3 = xp[1536];
            }

            if (t > 0) {
                const unsigned tt = (unsigned)t;
                u64 sa = (u64)(uintptr_t)(pk + (size_t)(t & 1) * HID + 2 * tid);
                uivec4 r;
                do {
                    asm volatile("global_load_dwordx4 %0, %1, off sc0 sc1\n\t"
                                 "s_waitcnt vmcnt(0)" : "=v"(r) : "v"(sa));
                } while (r.y != tt || r.w != tt);
                hbuf[2 * tid]     = __uint_as_float(r.x);
                hbuf[2 * tid + 1] = __uint_as_float(r.z);
                asm volatile("s_waitcnt lgkmcnt(0)" ::: "memory");
            }

            float a0 = 0.f, a1 = 0.f, a2 = 0.f, a3 = 0.f;
            float a4 = 0.f, a5 = 0.f, a6 = 0.f, a7 = 0.f;
            const f32x4* hp = (const f32x4*)&hbuf[wv * 128];
#pragma unroll
            for (int i = 0; i < 32; i += 8) {
                a0 = fma4(wreg[i],     hp[i],     a0);
                a1 = fma4(wreg[i + 1], hp[i + 1], a1);
                a2 = fma4(wreg[i + 2], hp[i + 2], a2);
                a3 = fma4(wreg[i + 3], hp[i + 3], a3);
                a4 = fma4(wreg[i + 4], hp[i + 4], a4);
                a5 = fma4(wreg[i + 5], hp[i + 5], a5);
                a6 = fma4(wreg[i + 6], hp[i + 6], a6);
                a7 = fma4(wreg[i + 7], hp[i + 7], a7);
            }
            pbuf[t & 1][tid] = ((a0 + a1) + (a2 + a3)) + ((a4 + a5) + (a6 + a7));
            __syncthreads();

            if (tid < 16) {
                const float* pb = pbuf[t & 1];
                float gi = pb[tid]      + pb[64 + tid]  + pb[128 + tid] + pb[192 + tid] + xg0;
                float gf = pb[16 + tid] + pb[80 + tid]  + pb[144 + tid] + pb[208 + tid] + xg1;
                float gg = pb[32 + tid] + pb[96 + tid]  + pb[160 + tid] + pb[224 + tid] + xg2;
                float go = pb[48 + tid] + pb[112 + tid] + pb[176 + tid] + pb[240 + tid] + xg3;
                float i_ = fsig(gi);
                float f_ = fsig(gf);
                float g_ = ftanh(gg);
                float o_ = fsig(go);
                c = fmaf(f_, c, i_ * g_);
                float h_ = o_ * ftanh(c);

                if (t < TLEN - 1) {   // latency-critical publish FIRST
                    u64 word = ((u64)(unsigned)(t + 1) << 32) | (u64)__float_as_uint(h_);
                    (void)__hip_atomic_exchange(
                        &pk[(size_t)((t + 1) & 1) * HID + wg * 16 + tid], word,
                        __ATOMIC_RELAXED, __HIP_MEMORY_SCOPE_AGENT);
                }
                // tagged A-word for the GEMM workers (off the critical path)
                short hh, hl; bf16split(h_, hh, hl);
                u64 aw = ((u64)(unsigned)(t + 1) << 32)
                       | (u64)((((unsigned)(unsigned short)hh) << 16) | (unsigned)(unsigned short)hl);
                __hip_atomic_store(&hs_t[(size_t)t * HID + wg * 16 + tid], aw,
                                   __ATOMIC_RELAXED, __HIP_MEMORY_SCOPE_AGENT);
                if (t == TLEN - 1) {
                    out_hT[wg * 16 + tid] = h_;
                    out_cT[wg * 16 + tid] = c;
                }
                if (tid == 0) {
                    if (t == 127 || t == 255 || t == 383 || t == 511)
                        __hip_atomic_fetch_add(&ready[t >> 7], 1,
                                               __ATOMIC_RELAXED, __HIP_MEMORY_SCOPE_AGENT);
                    if (t == TLEN - 1)
                        __hip_atomic_fetch_add(&ready[4], 1,
                                               __ATOMIC_RELAXED, __HIP_MEMORY_SCOPE_AGENT);
                }
            }
        }
        return;
    }

    // ==================== gemm worker role ====================
    const int w   = tid >> 6;
    const int l   = tid & 63;
    const int l15 = l & 15;
    const int lg  = l >> 4;
    const int sr  = tid >> 1;
    const int kh  = (tid & 1) * 16;

    for (;;) {
        if (tid == 0)
            s_idx = __hip_atomic_fetch_add(wq, 1, __ATOMIC_RELAXED, __HIP_MEMORY_SCOPE_AGENT);
        __syncthreads();
        const int idx = s_idx;
        __syncthreads();
        if (idx >= NTILES) break;
        const int tb = idx / NTILE_V;   // tb-major: tb0 tiles first
        const int vb = idx % NTILE_V;

        if (tid == 0) {                 // advisory gate (tags are the truth)
            while (__hip_atomic_load(&ready[tb], __ATOMIC_RELAXED,
                                     __HIP_MEMORY_SCOPE_AGENT) < NWG)
                __builtin_amdgcn_s_sleep(32);
        }
        __syncthreads();

        if (tb == 4) {
            // ---- slim path: only row 512 is valid ----
            float* hrow = (float*)&Ah[0][0];   // 2KB reuse
            for (int jj = tid; jj < HID; jj += 256) {
                u64 ad = (u64)(uintptr_t)(hs_t + (size_t)512 * HID + jj);
                uivec2 r2;
                do {
                    asm volatile("global_load_dwordx2 %0, %1, off sc0 sc1\n\t"
                                 "s_waitcnt vmcnt(0)" : "=v"(r2) : "v"(ad));
                } while (r2.y != 513u);
                hrow[jj] = __uint_as_float(r2.x & 0xffff0000u)
                         + __uint_as_float((r2.x & 0xffffu) << 16);
            }
            __syncthreads();
            if (tid < 128) {
                int col = vb * 128 + tid;
                const float4* wr = (const float4*)(W_out + (size_t)col * HID);
                float d0 = 0.f, d1 = 0.f, d2 = 0.f, d3 = 0.f;
#pragma unroll 4
                for (int k = 0; k < HID / 16; ++k) {
                    float4 w0 = wr[4*k], w1 = wr[4*k+1], w2 = wr[4*k+2], w3 = wr[4*k+3];
                    const float* hp = hrow + 16 * k;
                    d0 = fmaf(w0.x, hp[0],  fmaf(w0.y, hp[1],  fmaf(w0.z, hp[2],  fmaf(w0.w, hp[3],  d0))));
                    d1 = fmaf(w1.x, hp[4],  fmaf(w1.y, hp[5],  fmaf(w1.z, hp[6],  fmaf(w1.w, hp[7],  d1))));
                    d2 = fmaf(w2.x, hp[8],  fmaf(w2.y, hp[9],  fmaf(w2.z, hp[10], fmaf(w2.w, hp[11], d2))));
                    d3 = fmaf(w3.x, hp[12], fmaf(w3.y, hp[13], fmaf(w3.z, hp[14], fmaf(w3.w, hp[15], d3))));
                }
                out[(size_t)512 * VOCAB + col] = ((d0 + d1) + (d2 + d3)) + b_out[col];
            }
            __syncthreads();
            continue;
        }

        const int m0 = tb * 128, n0 = vb * 128;
        f32x4 acc[2][8];
#pragma unroll
        for (int s = 0; s < 2; ++s)
#pragma unroll
            for (int cc = 0; cc < 8; ++cc) acc[s][cc] = (f32x4){0.f, 0.f, 0.f, 0.f};

        for (int k0 = 0; k0 < HID; k0 += 32) {
            {   // A: tag-verified reads (tb<4 -> all 128 rows valid)
                uivec4 rr[8];
                u64 ad[8];
                unsigned tg[8];
#pragma unroll
                for (int it = 0; it < 8; ++it) {
                    int li = it * 256 + tid;
                    int m  = li >> 4;
                    int kp = li & 15;
                    ad[it] = (u64)(uintptr_t)(hs_t + (size_t)(m0 + m) * HID + k0 + kp * 2);
                    tg[it] = (unsigned)(m0 + m + 1);
                }
                bool done = false;
                while (!done) {
#pragma unroll
                    for (int it = 0; it < 8; ++it)
                        asm volatile("global_load_dwordx4 %0, %1, off sc0 sc1"
                                     : "=v"(rr[it]) : "v"(ad[it]));
                    asm volatile("s_waitcnt vmcnt(0)");
                    done = true;
#pragma unroll
                    for (int it = 0; it < 8; ++it)
                        if (rr[it].y != tg[it] || rr[it].w != tg[it]) done = false;
                }
#pragma unroll
                for (int it = 0; it < 8; ++it) {
                    int li = it * 256 + tid;
                    int m  = li >> 4;
                    int kp = li & 15;
                    Ah[m][kp * 2]     = (short)(rr[it].x >> 16);
                    Al[m][kp * 2]     = (short)(rr[it].x & 0xffffu);
                    Ah[m][kp * 2 + 1] = (short)(rr[it].z >> 16);
                    Al[m][kp * 2 + 1] = (short)(rr[it].z & 0xffffu);
                }
            }
            {   // B: from W_out fp32 (L3-resident) with in-kernel split
                const float4* bp = (const float4*)(W_out + (size_t)(n0 + sr) * HID + k0 + kh);
                float4 fb0 = bp[0], fb1 = bp[1], fb2 = bp[2], fb3 = bp[3];
                float fv[16] = { fb0.x,fb0.y,fb0.z,fb0.w, fb1.x,fb1.y,fb1.z,fb1.w,
                                 fb2.x,fb2.y,fb2.z,fb2.w, fb3.x,fb3.y,fb3.z,fb3.w };
#pragma unroll
                for (int g = 0; g < 2; ++g) {
                    union { short s[8]; bf16x8 v; } ph, pl;
#pragma unroll
                    for (int e = 0; e < 8; ++e) bf16split(fv[g * 8 + e], ph.s[e], pl.s[e]);
                    *(bf16x8*)&Bh[sr][kh + 8 * g] = ph.v;
                    *(bf16x8*)&Bl[sr][kh + 8 * g] = pl.v;
                }
            }
            __syncthreads();

            bf16x8 ah[2], al2[2];
#pragma unroll
            for (int s = 0; s < 2; ++s) {
                ah[s]  = *(const bf16x8*)&Ah[32 * w + 16 * s + l15][8 * lg];
                al2[s] = *(const bf16x8*)&Al[32 * w + 16 * s + l15][8 * lg];
            }
#pragma unroll
            for (int cc = 0; cc < 8; ++cc) {
                bf16x8 bh = *(const bf16x8*)&Bh[16 * cc + l15][8 * lg];
                bf16x8 bl = *(const bf16x8*)&Bl[16 * cc + l15][8 * lg];
#pragma unroll
                for (int s = 0; s < 2; ++s) {
                    acc[s][cc] = __builtin_amdgcn_mfma_f32_16x16x32_bf16(ah[s],  bh, acc[s][cc], 0, 0, 0);
                    acc[s][cc] = __builtin_amdgcn_mfma_f32_16x16x32_bf16(ah[s],  bl, acc[s][cc], 0, 0, 0);
                    acc[s][cc] = __builtin_amdgcn_mfma_f32_16x16x32_bf16(al2[s], bh, acc[s][cc], 0, 0, 0);
                }
            }
            __syncthreads();
        }

#pragma unroll
        for (int cc = 0; cc < 8; ++cc) {
            int col = n0 + 16 * cc + l15;
            float bo = b_out[col];
#pragma unroll
            for (int s = 0; s < 2; ++s) {
                int rbase = m0 + 32 * w + 16 * s + lg * 4;
#pragma unroll
                for (int r = 0; r < 4; ++r) {
                    out[(size_t)(rbase + r) * VOCAB + col] = acc[s][cc][r] + bo;
                }
            }
        }
    }
}

// ---------------------------------------------------------------------------
extern "C" void kernel_launch(void* const* d_in, const int* in_sizes, int n_in,
                              void* d_out, int out_size, void* d_ws, size_t ws_size,
                              hipStream_t stream)
{
    const int*   seq   = (const int*)  d_in[0];
    const float* h0    = (const float*)d_in[1];
    const float* c0    = (const float*)d_in[2];
    const float* emb   = (const float*)d_in[3];
    const float* W_ih  = (const float*)d_in[4];
    const float* W_hh  = (const float*)d_in[5];
    const float* b_ih  = (const float*)d_in[6];
    const float* b_hh  = (const float*)d_in[7];
    const float* W_out = (const float*)d_in[8];
    const float* b_out = (const float*)d_in[9];

    float* out_logits = (float*)d_out;                      // [513][32000]
    float* out_hT     = out_logits + (size_t)TLEN * VOCAB;  // [512]
    float* out_cT     = out_hT + HID;                       // [512]

    // workspace layout
    char*  base = (char*)d_ws;
    float* Xg   = (float*)base;                              // 4,202,496 B
    u64*   pk   = (u64*)(base + 4202496);                    //     8,192 B
    u64*   hs_t = (u64*)(base + 4202496 + 8192);             // 2,101,248 B
    int*   flags= (int*)(base + 4202496 + 8192 + 2101248);   //        64 B

    precompute_gates<<<dim3(33, 8), 256, 0, stream>>>(seq, emb, W_ih, b_ih, b_hh,
                                                      Xg, pk, flags);
    mega<<<GRID_MEGA, 256, 0, stream>>>(Xg, W_hh, h0, c0, W_out, b_out,
                                        pk, hs_t, flags,
                                        out_logits, out_hT, out_cT);
}